// Round 6
// baseline (761.426 us; speedup 1.0000x reference)
//
#include <hip/hip_runtime.h>

// RobustAttention: blockwise (w=15) causal cosFormer linear attention.
// scores[l,j] = cos(th_l - th_j) * <relu(q_l), relu(k_j)>, j<=l
// out[l] = sum_j scores[l,j] * relu(v_j) / max(sum_j scores[l,j], 1e-6)
//
// R9: R8 proved the kernel is latency-bound at the STRUCTURE level: barriers
// + full staging drains serialize all 4 waves of a WG together, occupancy
// pinned ~18% regardless of LDS cap (R6), VALU 16%, HBM 42%. The producer
// and consumer of every LDS tile is the same 16-lane group -> the workgroup
// coupling is artificial.
// Fix: wave = workgroup. 64-thread WGs, 4 tiles/wave, private 16,320 B slab.
//  - ALL __syncthreads() removed. A wave runs in lockstep and LDS ops
//    complete in-order per wave; the q-read -> k-overwrite WAR hazard needs
//    only s_waitcnt lgkmcnt(0) (+ "memory" clobber vs compile-time reorder).
//  - 5120 independent WGs; LDS 16,384/WG -> 10 resident/CU (was 8 waves,
//    barrier-locked). Waves progress through their own stage/compute phases
//    independently -> memory latency of one wave hides under compute of
//    others.
//  - __launch_bounds__(64,3): VGPR cap 170 > ~140 live set (no R4/R5/R7
//    spill repeat), with headroom for the compiler to hoist v loads under
//    phase 1.
//  - q and k both staged coalesced through the slab (R8's layout, stride
//    17/255 float4: 2-way bank = free). Phase 2 shuffle unchanged.
//  - NT output stores kept.

namespace {

constexpr int W        = 15;            // block_size (rows per tile)
constexpr int CH       = 16;            // float4 per row (D=64)
constexpr int TILE4    = W * CH;        // 240 float4 per tile
constexpr int TPW      = 4;             // tiles per wave (= per workgroup)
constexpr int NTHREADS = 64;            // one wave
constexpr int RSTRIDE4 = CH + 1;        // 17: padded row stride (float4)
constexpr int TSTRIDE4 = W * RSTRIDE4;  // 255: padded tile stride (float4)

typedef float f32x4_n __attribute__((ext_vector_type(4)));

__device__ __forceinline__ float4 relu4(float4 a) {
    return make_float4(fmaxf(a.x, 0.f), fmaxf(a.y, 0.f),
                       fmaxf(a.z, 0.f), fmaxf(a.w, 0.f));
}

__global__ __launch_bounds__(NTHREADS, 3)
void robust_attn_kernel(const float4* __restrict__ q4,
                        const float4* __restrict__ k4,
                        const float4* __restrict__ v4,
                        float4* __restrict__ o4,
                        int nblocks)
{
    __shared__ float4 slab[TPW * TSTRIDE4];   // 4*255*16 = 16,320 B

    const int tid  = threadIdx.x;              // == lane (one wave)
    const int lane = tid & 15;                 // row l (ph1) / d-chunk (ph2)
    const int t    = tid >> 4;                 // tile within wave (0..3)
    const int g0   = blockIdx.x * TPW;
    const int g    = g0 + t;
    const bool active = (g < nblocks);
    const bool ph1    = active && (lane < W);

    // ---------- stage relu(q) into the slab, row-padded layout -------------
    {
        const size_t base = (size_t)g0 * TILE4;
#pragma unroll
        for (int r = 0; r < (TPW * TILE4) / NTHREADS; ++r) {   // 15 iters
            const int idx = tid + r * NTHREADS;
            const int tt  = idx / TILE4;
            const int pos = idx - tt * TILE4;
            const int rr  = pos >> 4;          // row within tile
            const int cc  = pos & 15;          // float4 within row
            float4 x = make_float4(0.f, 0.f, 0.f, 0.f);
            if (g0 + tt < nblocks) x = q4[base + idx];
            slab[tt * TSTRIDE4 + rr * RSTRIDE4 + cc] = relu4(x);
        }
    }
    // wave-lockstep + in-order LDS: writes above land before reads below;
    // waitcnt+clobber also stops compile-time reordering.
    asm volatile("s_waitcnt lgkmcnt(0)" ::: "memory");

    // ---------- each ph1 lane pulls its q row from the slab ----------------
    float4 qr[CH];
    if (ph1) {
        const float4* __restrict__ ql = &slab[t * TSTRIDE4 + lane * RSTRIDE4];
#pragma unroll
        for (int c = 0; c < CH; ++c) qr[c] = ql[c];
    }
    // WAR hazard: all q reads must complete before k overwrites the slab.
    asm volatile("s_waitcnt lgkmcnt(0)" ::: "memory");

    // ---------- restage relu(k) into the same slab -------------------------
    {
        const size_t base = (size_t)g0 * TILE4;
#pragma unroll
        for (int r = 0; r < (TPW * TILE4) / NTHREADS; ++r) {   // 15 iters
            const int idx = tid + r * NTHREADS;
            const int tt  = idx / TILE4;
            const int pos = idx - tt * TILE4;
            const int rr  = pos >> 4;
            const int cc  = pos & 15;
            float4 x = make_float4(0.f, 0.f, 0.f, 0.f);
            if (g0 + tt < nblocks) x = k4[base + idx];
            slab[tt * TSTRIDE4 + rr * RSTRIDE4 + cc] = relu4(x);
        }
    }
    asm volatile("s_waitcnt lgkmcnt(0)" ::: "memory");

    // ---------- phase 1: dots (k broadcast from slab), weights, normalize --
    float s[W];
#pragma unroll
    for (int j = 0; j < W; ++j) s[j] = 0.f;

    if (ph1) {
        const int l = lane;
        const float4* __restrict__ kl = &slab[t * TSTRIDE4];
#pragma unroll
        for (int j = 0; j < W; ++j) {
            float acc = 0.f;
#pragma unroll
            for (int c = 0; c < CH; ++c) {
                const float4 kk = kl[j * RSTRIDE4 + c];
                acc = fmaf(qr[c].x, kk.x, acc);
                acc = fmaf(qr[c].y, kk.y, acc);
                acc = fmaf(qr[c].z, kk.z, acc);
                acc = fmaf(qr[c].w, kk.w, acc);
            }
            s[j] = acc;
        }

        const float step = 1.57079632679489662f / (float)W;  // (pi/2)/15
        float denom = 0.f;
#pragma unroll
        for (int j = 0; j < W; ++j) {
            float wc = __cosf(step * (float)(l - j));
            float tv = (j <= l) ? s[j] * wc : 0.f;
            s[j] = tv;
            denom += tv;
        }
        const float inv = 1.f / fmaxf(denom, 1e-6f);
#pragma unroll
        for (int j = 0; j < W; ++j) s[j] *= inv;
    }

    // ---------- phase 2: out = S @ relu(v); weights via wave shuffle -------
    if (active) {
        const float4* __restrict__ vp = v4 + (size_t)g * TILE4 + lane;
        float4* __restrict__ op       = o4 + (size_t)g * TILE4 + lane;

        float4 vv[W];
#pragma unroll
        for (int j = 0; j < W; ++j) vv[j] = relu4(vp[j * CH]);

        const int tbase = tid & 48;   // tile base lane within the wave
#pragma unroll
        for (int l = 0; l < W; ++l) {
            float ax = 0.f, ay = 0.f, az = 0.f, aw = 0.f;
#pragma unroll
            for (int j = 0; j <= l; ++j) {     // causal
                const float w = __shfl(s[j], tbase + l, 64);
                ax = fmaf(w, vv[j].x, ax);
                ay = fmaf(w, vv[j].y, ay);
                az = fmaf(w, vv[j].z, az);
                aw = fmaf(w, vv[j].w, aw);
            }
            // nontemporal: output stream must not evict L3-resident inputs
            f32x4_n val = {ax, ay, az, aw};
            __builtin_nontemporal_store(val, (f32x4_n*)(op + l * CH));
        }
    }
}

}  // namespace

extern "C" void kernel_launch(void* const* d_in, const int* in_sizes, int n_in,
                              void* d_out, int out_size, void* d_ws, size_t ws_size,
                              hipStream_t stream) {
    const float4* q = (const float4*)d_in[0];
    const float4* k = (const float4*)d_in[1];
    const float4* v = (const float4*)d_in[2];
    float4* out = (float4*)d_out;

    const int total   = in_sizes[0];           // B*H*L*D
    const int nblocks = total / (W * CH * 4);  // 20480 for the bench shape
    const int wgs     = (nblocks + TPW - 1) / TPW;

    robust_attn_kernel<<<wgs, NTHREADS, 0, stream>>>(q, k, v, out, nblocks);
}

// Round 7
// 76.837 us; speedup vs baseline: 9.9096x; 9.9096x over previous
//
#include <hip/hip_runtime.h>

// RobustAttention: blockwise (w=15) causal cosFormer linear attention.
// scores[l,j] = cos(th_l - th_j) * <relu(q_l), relu(k_j)>, j<=l
// out[l] = sum_j scores[l,j] * relu(v_j) / max(sum_j scores[l,j], 1e-6)
//
// R10: R9's wave-per-WG restructure was poisoned by its own fences: the
// asm volatile "memory" clobbers made qr[]/s[]/vv[] addressable -> SROA
// failed -> arrays in scratch (VGPR 84, +1.5 GB scratch traffic). The
// wave-independence mechanism was never tested (occupancy still rose
// 18->24% under the spills).
// R10 = R9 with the fences swapped for __syncthreads(): in a single-wave
// workgroup it lowers to just the LDS-ordering waitcnt (s_barrier is
// trivial/elided at blockDim<=64), gives exactly the ordering we need,
// and is proven (R8) not to break array promotion.
//  - 64-thread WGs = 1 wave, 4 tiles/wave, private 16,384 B slab.
//  - 160 KiB / 16 KiB = EXACTLY 10 independent WGs/CU (vs R8's 8 waves in
//    2 barrier-coupled groups) -> decoupled latency hiding.
//  - __launch_bounds__(64,2): VGPR cap 256, zero allocator pressure.
//  - q staged coalesced -> per-lane row reads (stride 17 float4, 2-way
//    bank = free); k restaged into same slab -> broadcast reads.
//  - NT output stores kept.
// Red line: WRITE_SIZE must be 76,800 KB.

namespace {

constexpr int W        = 15;            // block_size (rows per tile)
constexpr int CH       = 16;            // float4 per row (D=64)
constexpr int TILE4    = W * CH;        // 240 float4 per tile
constexpr int TPW      = 4;             // tiles per wave (= per workgroup)
constexpr int NTHREADS = 64;            // one wave
constexpr int RSTRIDE4 = CH + 1;        // 17: padded row stride (float4)
constexpr int TSTRIDE4 = W * RSTRIDE4;  // 255: padded tile stride (float4)

typedef float f32x4_n __attribute__((ext_vector_type(4)));

__device__ __forceinline__ float4 relu4(float4 a) {
    return make_float4(fmaxf(a.x, 0.f), fmaxf(a.y, 0.f),
                       fmaxf(a.z, 0.f), fmaxf(a.w, 0.f));
}

__global__ __launch_bounds__(NTHREADS, 2)
void robust_attn_kernel(const float4* __restrict__ q4,
                        const float4* __restrict__ k4,
                        const float4* __restrict__ v4,
                        float4* __restrict__ o4,
                        int nblocks)
{
    __shared__ float4 slab[TPW * TSTRIDE4];   // 4*255*16 = 16,320 B

    const int tid  = threadIdx.x;              // == lane (one wave)
    const int lane = tid & 15;                 // row l (ph1) / d-chunk (ph2)
    const int t    = tid >> 4;                 // tile within wave (0..3)
    const int g0   = blockIdx.x * TPW;
    const int g    = g0 + t;
    const bool active = (g < nblocks);
    const bool ph1    = active && (lane < W);

    // ---------- stage relu(q) into the slab, row-padded layout -------------
    {
        const size_t base = (size_t)g0 * TILE4;
#pragma unroll
        for (int r = 0; r < (TPW * TILE4) / NTHREADS; ++r) {   // 15 iters
            const int idx = tid + r * NTHREADS;
            const int tt  = idx / TILE4;
            const int pos = idx - tt * TILE4;
            const int rr  = pos >> 4;          // row within tile
            const int cc  = pos & 15;          // float4 within row
            float4 x = make_float4(0.f, 0.f, 0.f, 0.f);
            if (g0 + tt < nblocks) x = q4[base + idx];
            slab[tt * TSTRIDE4 + rr * RSTRIDE4 + cc] = relu4(x);
        }
    }
    __syncthreads();   // single-wave WG: lowers to lgkmcnt drain only

    // ---------- each ph1 lane pulls its q row from the slab ----------------
    float4 qr[CH];
    if (ph1) {
        const float4* __restrict__ ql = &slab[t * TSTRIDE4 + lane * RSTRIDE4];
#pragma unroll
        for (int c = 0; c < CH; ++c) qr[c] = ql[c];
    }
    __syncthreads();   // WAR: q reads complete before k overwrites the slab

    // ---------- restage relu(k) into the same slab -------------------------
    {
        const size_t base = (size_t)g0 * TILE4;
#pragma unroll
        for (int r = 0; r < (TPW * TILE4) / NTHREADS; ++r) {   // 15 iters
            const int idx = tid + r * NTHREADS;
            const int tt  = idx / TILE4;
            const int pos = idx - tt * TILE4;
            const int rr  = pos >> 4;
            const int cc  = pos & 15;
            float4 x = make_float4(0.f, 0.f, 0.f, 0.f);
            if (g0 + tt < nblocks) x = k4[base + idx];
            slab[tt * TSTRIDE4 + rr * RSTRIDE4 + cc] = relu4(x);
        }
    }
    __syncthreads();

    // ---------- phase 1: dots (k broadcast from slab), weights, normalize --
    float s[W];
#pragma unroll
    for (int j = 0; j < W; ++j) s[j] = 0.f;

    if (ph1) {
        const int l = lane;
        const float4* __restrict__ kl = &slab[t * TSTRIDE4];
#pragma unroll
        for (int j = 0; j < W; ++j) {
            float acc = 0.f;
#pragma unroll
            for (int c = 0; c < CH; ++c) {
                const float4 kk = kl[j * RSTRIDE4 + c];
                acc = fmaf(qr[c].x, kk.x, acc);
                acc = fmaf(qr[c].y, kk.y, acc);
                acc = fmaf(qr[c].z, kk.z, acc);
                acc = fmaf(qr[c].w, kk.w, acc);
            }
            s[j] = acc;
        }

        const float step = 1.57079632679489662f / (float)W;  // (pi/2)/15
        float denom = 0.f;
#pragma unroll
        for (int j = 0; j < W; ++j) {
            float wc = __cosf(step * (float)(l - j));
            float tv = (j <= l) ? s[j] * wc : 0.f;
            s[j] = tv;
            denom += tv;
        }
        const float inv = 1.f / fmaxf(denom, 1e-6f);
#pragma unroll
        for (int j = 0; j < W; ++j) s[j] *= inv;
    }

    // ---------- phase 2: out = S @ relu(v); weights via wave shuffle -------
    if (active) {
        const float4* __restrict__ vp = v4 + (size_t)g * TILE4 + lane;
        float4* __restrict__ op       = o4 + (size_t)g * TILE4 + lane;

        float4 vv[W];
#pragma unroll
        for (int j = 0; j < W; ++j) vv[j] = relu4(vp[j * CH]);

        const int tbase = tid & 48;   // tile base lane within the wave
#pragma unroll
        for (int l = 0; l < W; ++l) {
            float ax = 0.f, ay = 0.f, az = 0.f, aw = 0.f;
#pragma unroll
            for (int j = 0; j <= l; ++j) {     // causal
                const float w = __shfl(s[j], tbase + l, 64);
                ax = fmaf(w, vv[j].x, ax);
                ay = fmaf(w, vv[j].y, ay);
                az = fmaf(w, vv[j].z, az);
                aw = fmaf(w, vv[j].w, aw);
            }
            // nontemporal: output stream must not evict L3-resident inputs
            f32x4_n val = {ax, ay, az, aw};
            __builtin_nontemporal_store(val, (f32x4_n*)(op + l * CH));
        }
    }
}

}  // namespace

extern "C" void kernel_launch(void* const* d_in, const int* in_sizes, int n_in,
                              void* d_out, int out_size, void* d_ws, size_t ws_size,
                              hipStream_t stream) {
    const float4* q = (const float4*)d_in[0];
    const float4* k = (const float4*)d_in[1];
    const float4* v = (const float4*)d_in[2];
    float4* out = (float4*)d_out;

    const int total   = in_sizes[0];           // B*H*L*D
    const int nblocks = total / (W * CH * 4);  // 20480 for the bench shape
    const int wgs     = (nblocks + TPW - 1) / TPW;

    robust_attn_kernel<<<wgs, NTHREADS, 0, stream>>>(q, k, v, out, nblocks);
}